// Round 14
// baseline (413.928 us; speedup 1.0000x reference)
//
#include <hip/hip_runtime.h>
#include <hip/hip_bf16.h>

#define B_ 4
#define S_ 2048
#define H_ 8
#define E_ 64
#define NW 4      // waves per attention block
#define QB 16     // q rows per wave
#define KT 64     // k/v tile size
#define NT (S_ / KT)
#define HSPLIT 4  // proj: head-groups per s-tile (2 heads per block)

typedef __attribute__((ext_vector_type(8))) short bf16x8v;
typedef __attribute__((ext_vector_type(4))) float f32x4v;

static __device__ __forceinline__ unsigned short f2bf(float f) {
    __hip_bfloat16 h = __float2bfloat16(f);
    return *reinterpret_cast<unsigned short*>(&h);
}

// async global->LDS DMA, 16B/lane
static __device__ __forceinline__ void gl_lds16(const void* g, void* lds) {
    __builtin_amdgcn_global_load_lds(
        (const __attribute__((address_space(1))) unsigned int*)g,
        (__attribute__((address_space(3))) unsigned int*)lds, 16, 0, 0);
}

// ---------------------------------------------------------------------------
// Projection (R9, HBM-BW bound): q scaled into exp2 domain, K plain,
// V pre-transposed. grid = B * S/16 * HSPLIT, block = 192.
// ---------------------------------------------------------------------------
__global__ __launch_bounds__(192)
void proj_kernel(const float* __restrict__ query, const float* __restrict__ key,
                 const float* __restrict__ value,
                 const float* __restrict__ Wq, const float* __restrict__ bq,
                 const float* __restrict__ Wk, const float* __restrict__ bk,
                 const float* __restrict__ Wv, const float* __restrict__ bv,
                 __hip_bfloat16* __restrict__ qp, __hip_bfloat16* __restrict__ kp,
                 __hip_bfloat16* __restrict__ vtp)
{
    const int tid  = threadIdx.x;
    const int wave = tid >> 6;
    const int lane = tid & 63;
    const int lr   = lane & 15;
    const int lh   = lane >> 4;
    const int ntile = S_ / 16;
    const int hb    = blockIdx.x % HSPLIT;
    const int sbase = ((blockIdx.x / HSPLIT) % ntile) * 16;
    const int b     = blockIdx.x / (ntile * HSPLIT);

    const float* x    = (wave == 0) ? query : (wave == 1) ? key : value;
    const float* W    = (wave == 0) ? Wq    : (wave == 1) ? Wk  : Wv;
    const float* bias = (wave == 0) ? bq    : (wave == 1) ? bk  : bv;

    bf16x8v wf[4][2];
#pragma unroll
    for (int cb = 0; cb < 4; ++cb)
#pragma unroll
        for (int hf = 0; hf < 2; ++hf)
#pragma unroll
            for (int j = 0; j < 8; ++j) {
                int e = lh * 8 + j + 32 * hf;
                wf[cb][hf][j] = (short)f2bf(W[e * E_ + cb * 16 + lr]);
            }

    float4 bias4[4];
    float  bvals[4];
#pragma unroll
    for (int cb = 0; cb < 4; ++cb) {
        bias4[cb] = *reinterpret_cast<const float4*>(bias + cb * 16 + 4 * lh);
        bvals[cb] = bias[cb * 16 + lr];
    }

    const float QSCALE = 0.18033688011112042f;   // log2e / 8

#pragma unroll
    for (int hi = 0; hi < H_ / HSPLIT; ++hi) {
        const int h = hb * (H_ / HSPLIT) + hi;
        const float* xrow = x + (((size_t)b * S_ + sbase + lr) * H_ + h) * E_;
        const float4* xr = reinterpret_cast<const float4*>(xrow);
        float4 a0 = xr[lh * 2], a1 = xr[lh * 2 + 1];
        float4 a2 = xr[8 + lh * 2], a3 = xr[8 + lh * 2 + 1];
        bf16x8v af[2];
        af[0][0] = (short)f2bf(a0.x); af[0][1] = (short)f2bf(a0.y);
        af[0][2] = (short)f2bf(a0.z); af[0][3] = (short)f2bf(a0.w);
        af[0][4] = (short)f2bf(a1.x); af[0][5] = (short)f2bf(a1.y);
        af[0][6] = (short)f2bf(a1.z); af[0][7] = (short)f2bf(a1.w);
        af[1][0] = (short)f2bf(a2.x); af[1][1] = (short)f2bf(a2.y);
        af[1][2] = (short)f2bf(a2.z); af[1][3] = (short)f2bf(a2.w);
        af[1][4] = (short)f2bf(a3.x); af[1][5] = (short)f2bf(a3.y);
        af[1][6] = (short)f2bf(a3.z); af[1][7] = (short)f2bf(a3.w);

        if (wave < 2) {
            __hip_bfloat16* dst = (wave == 0) ? qp : kp;
            const float scl = (wave == 0) ? QSCALE : 1.0f;
#pragma unroll
            for (int cb = 0; cb < 4; ++cb) {
                f32x4v acc = {0.f, 0.f, 0.f, 0.f};
                acc = __builtin_amdgcn_mfma_f32_16x16x32_bf16(wf[cb][0], af[0], acc, 0, 0, 0);
                acc = __builtin_amdgcn_mfma_f32_16x16x32_bf16(wf[cb][1], af[1], acc, 0, 0, 0);
                ushort4 o;
                o.x = f2bf((acc[0] + bias4[cb].x) * scl);
                o.y = f2bf((acc[1] + bias4[cb].y) * scl);
                o.z = f2bf((acc[2] + bias4[cb].z) * scl);
                o.w = f2bf((acc[3] + bias4[cb].w) * scl);
                *reinterpret_cast<ushort4*>(
                    (unsigned short*)dst +
                    (((size_t)b * H_ + h) * S_ + sbase + lr) * E_ + cb * 16 + 4 * lh) = o;
            }
        } else {
#pragma unroll
            for (int cb = 0; cb < 4; ++cb) {
                f32x4v acc = {0.f, 0.f, 0.f, 0.f};
                acc = __builtin_amdgcn_mfma_f32_16x16x32_bf16(af[0], wf[cb][0], acc, 0, 0, 0);
                acc = __builtin_amdgcn_mfma_f32_16x16x32_bf16(af[1], wf[cb][1], acc, 0, 0, 0);
                float bv4 = bvals[cb];
                ushort4 o;
                o.x = f2bf(acc[0] + bv4);
                o.y = f2bf(acc[1] + bv4);
                o.z = f2bf(acc[2] + bv4);
                o.w = f2bf(acc[3] + bv4);
                *reinterpret_cast<ushort4*>(
                    (unsigned short*)vtp +
                    (((size_t)b * H_ + h) * E_ + cb * 16 + lr) * S_ + sbase + 4 * lh) = o;
            }
        }
    }
}

// ---------------------------------------------------------------------------
// Flash attention = R10 (best: gl_lds dbuf + counted boundary + strided
// coalesced mask + raw exp2) with the mask stream re-grouped into 2-TILE
// BURSTS: 8 int4 loads covering 512B contiguous per q-row, issued mid-odd-
// tile (after the previous quad dies). Boundaries: odd = vmcnt(8) (retire
// staging, keep mask in flight), even = vmcnt(0) (conservative).
// grid = B*H * S/(QB*NW) = 1024, block = 256
// ---------------------------------------------------------------------------
__global__ __launch_bounds__(256, 4)
void attn_kernel(const __hip_bfloat16* __restrict__ qp,
                 const __hip_bfloat16* __restrict__ kp,
                 const __hip_bfloat16* __restrict__ vtp,
                 const int* __restrict__ mask,
                 float* __restrict__ out)
{
    __shared__ unsigned short Kt[2][KT * E_];    // swizzled [k][e], dbuf
    __shared__ unsigned short Vs[2][KT * E_];    // swizzled [e][k], dbuf
    __shared__ unsigned short Pt[NW][16 * KT];   // swizzled [q][k], per wave

    const int tid  = threadIdx.x;
    const int wave = tid >> 6;
    const int lane = tid & 63;
    const int lr   = lane & 15;
    const int lh   = lane >> 4;
    const int nqt  = S_ / (QB * NW);
    const int bh   = blockIdx.x / nqt;
    const int qt   = blockIdx.x % nqt;
    const int qbase = qt * (QB * NW) + wave * QB;

    const __hip_bfloat16* qrow = qp + ((size_t)bh * S_ + qbase + lr) * E_;
    bf16x8v aq0 = *reinterpret_cast<const bf16x8v*>(qrow + lh * 8);
    bf16x8v aq1 = *reinterpret_cast<const bf16x8v*>(qrow + lh * 8 + 32);

    float psum[4];
    f32x4v Oa[4];
#pragma unroll
    for (int r = 0; r < 4; ++r) psum[r] = 0.f;
#pragma unroll
    for (int eb = 0; eb < 4; ++eb) Oa[eb] = {0.f, 0.f, 0.f, 0.f};

    const char* kgb = (const char*)(kp  + (size_t)bh * S_ * E_);
    const char* vgb = (const char*)(vtp + (size_t)bh * E_ * S_);
    // mask base: lane covers row lr, 16B chunk lh; group g = bytes
    // [g*512, g*512+512) of the row (2 tiles x 256B)
    const char* mwb = (const char*)mask +
        (((size_t)bh * S_ + qbase + lr) * S_) * 4 + lh * 16;

    const int rowA = wave * 16 + (lane >> 3);
    const int rowB = rowA + 8;
    const int e2   = (((lane & 7) ^ (lane >> 3)) << 4);
    const size_t koffA = (size_t)rowA * 128 + e2;
    const size_t koffB = (size_t)rowB * 128 + e2;
    const size_t voffA = (size_t)rowA * (S_ * 2) + e2;
    const size_t voffB = (size_t)rowB * (S_ * 2) + e2;

    char* Kt0 = (char*)(Kt[0]); char* Kt1 = (char*)(Kt[1]);
    char* Vs0 = (char*)(Vs[0]); char* Vs1 = (char*)(Vs[1]);
    char* PtB = (char*)(Pt[wave]);

    // mask regs: one 2-tile group (512B/row). m0..m3 = even tile, m4..m7 = odd
    int4 m0, m1, m2, m3, m4, m5, m6, m7;

    // ---- prologue: stage tile 0 (oldest 4 vmem); group-0 mask burst (8)
    gl_lds16(kgb + koffA, Kt0 + wave * 2048);
    gl_lds16(kgb + koffB, Kt0 + wave * 2048 + 1024);
    gl_lds16(vgb + voffA, Vs0 + wave * 2048);
    gl_lds16(vgb + voffB, Vs0 + wave * 2048 + 1024);
    __builtin_amdgcn_sched_barrier(0);
    m0 = *reinterpret_cast<const int4*>(mwb);
    m1 = *reinterpret_cast<const int4*>(mwb + 64);
    m2 = *reinterpret_cast<const int4*>(mwb + 128);
    m3 = *reinterpret_cast<const int4*>(mwb + 192);
    m4 = *reinterpret_cast<const int4*>(mwb + 256);
    m5 = *reinterpret_cast<const int4*>(mwb + 320);
    m6 = *reinterpret_cast<const int4*>(mwb + 384);
    m7 = *reinterpret_cast<const int4*>(mwb + 448);
    __builtin_amdgcn_sched_barrier(0);
    asm volatile("s_waitcnt vmcnt(8)" ::: "memory");
    __builtin_amdgcn_s_barrier();
    __builtin_amdgcn_sched_barrier(0);

    for (int g = 0; g < NT / 2; ++g) {
        // ================= EVEN tile: kt = 2g (uses buf0, stages buf1) =====
        {
            const int kt = 2 * g;
            const int kb = kt * KT;
            // staging for kt+1 (always exists: kt <= 30)
            {
                const size_t kadd = (size_t)(kb + KT) * 128;
                const size_t vadd = (size_t)(kb + KT) * 2;
                gl_lds16(kgb + kadd + koffA, Kt1 + wave * 2048);
                gl_lds16(kgb + kadd + koffB, Kt1 + wave * 2048 + 1024);
                gl_lds16(vgb + vadd + voffA, Vs1 + wave * 2048);
                gl_lds16(vgb + vadd + voffB, Vs1 + wave * 2048 + 1024);
            }
            __builtin_amdgcn_sched_barrier(0);

            // pack even-tile mask from m0..m3
            unsigned long long wm;
            {
                unsigned n0 = (m0.x & 1) | ((m0.y & 1) << 1) | ((m0.z & 1) << 2) | ((m0.w & 1) << 3);
                unsigned n1 = (m1.x & 1) | ((m1.y & 1) << 1) | ((m1.z & 1) << 2) | ((m1.w & 1) << 3);
                unsigned n2 = (m2.x & 1) | ((m2.y & 1) << 1) | ((m2.z & 1) << 2) | ((m2.w & 1) << 3);
                unsigned n3 = (m3.x & 1) | ((m3.y & 1) << 1) | ((m3.z & 1) << 2) | ((m3.w & 1) << 3);
                int sh = lh * 4;
                wm = ((unsigned long long)n0 << sh) |
                     ((unsigned long long)n1 << (sh + 16)) |
                     ((unsigned long long)n2 << (sh + 32)) |
                     ((unsigned long long)n3 << (sh + 48));
                wm |= __shfl_xor(wm, 16);
                wm |= __shfl_xor(wm, 32);
            }

            // QK^T from Kt0
            f32x4v sc[4];
#pragma unroll
            for (int cb = 0; cb < 4; ++cb) {
                int kcol = cb * 16 + lr;
                bf16x8v bk0 = *reinterpret_cast<bf16x8v*>(
                    Kt0 + ((kcol * 128 + lh * 16) ^ ((kcol & 7) << 4)));
                bf16x8v bk1 = *reinterpret_cast<bf16x8v*>(
                    Kt0 + ((kcol * 128 + 64 + lh * 16) ^ ((kcol & 7) << 4)));
                f32x4v a = {0.f, 0.f, 0.f, 0.f};
                a = __builtin_amdgcn_mfma_f32_16x16x32_bf16(aq0, bk0, a, 0, 0, 0);
                a = __builtin_amdgcn_mfma_f32_16x16x32_bf16(aq1, bk1, a, 0, 0, 0);
                sc[cb] = a;
            }
#pragma unroll
            for (int r = 0; r < 4; ++r) {
                int q = 4 * lh + r;
                float rs = 0.f;
#pragma unroll
                for (int cb = 0; cb < 4; ++cb) {
                    float pv = __builtin_amdgcn_exp2f(sc[cb][r]);
                    rs += pv;
                    *reinterpret_cast<unsigned short*>(
                        PtB + ((q * 128 + (cb * 16 + lr) * 2) ^ ((q & 7) << 4))) = f2bf(pv);
                }
                psum[r] += rs;
            }
#pragma unroll
            for (int mh = 0; mh < 2; ++mh) {
                int k0 = mh * 32 + lh * 8;
                bf16x8v pa = *reinterpret_cast<bf16x8v*>(
                    PtB + ((lr * 128 + k0 * 2) ^ ((lr & 7) << 4)));
                unsigned mby = (unsigned)(wm >> ((mh * 4 + lh) * 8)) & 0xffu;
#pragma unroll
                for (int j = 0; j < 8; ++j)
                    pa[j] = (mby & (1u << j)) ? pa[j] : (short)0;
#pragma unroll
                for (int eb = 0; eb < 4; ++eb) {
                    int e = eb * 16 + lr;
                    bf16x8v vb = *reinterpret_cast<bf16x8v*>(
                        Vs0 + ((e * 128 + k0 * 2) ^ ((e & 7) << 4)));
                    Oa[eb] = __builtin_amdgcn_mfma_f32_16x16x32_bf16(pa, vb, Oa[eb], 0, 0, 0);
                }
            }
            // even boundary: conservative full drain (mask loads ~1 tile old)
            asm volatile("s_waitcnt vmcnt(0)" ::: "memory");
            __builtin_amdgcn_s_barrier();
            __builtin_amdgcn_sched_barrier(0);
        }

        // ================= ODD tile: kt = 2g+1 (uses buf1, stages buf0) ====
        {
            const int kt = 2 * g + 1;
            const int kb = kt * KT;
            const bool stg = (kt + 1 < NT);
            if (stg) {
                const size_t kadd = (size_t)(kb + KT) * 128;
                const size_t vadd = (size_t)(kb + KT) * 2;
                gl_lds16(kgb + kadd + koffA, Kt0 + wave * 2048);
                gl_lds16(kgb + kadd + koffB, Kt0 + wave * 2048 + 1024);
                gl_lds16(vgb + vadd + voffA, Vs0 + wave * 2048);
                gl_lds16(vgb + vadd + voffB, Vs0 + wave * 2048 + 1024);
            }
            __builtin_amdgcn_sched_barrier(0);

            // pack odd-tile mask from m4..m7 (consumed BEFORE the reload)
            unsigned long long wm;
            {
                unsigned n0 = (m4.x & 1) | ((m4.y & 1) << 1) | ((m4.z & 1) << 2) | ((m4.w & 1) << 3);
                unsigned n1 = (m5.x & 1) | ((m5.y & 1) << 1) | ((m5.z & 1) << 2) | ((m5.w & 1) << 3);
                unsigned n2 = (m6.x & 1) | ((m6.y & 1) << 1) | ((m6.z & 1) << 2) | ((m6.w & 1) << 3);
                unsigned n3 = (m7.x & 1) | ((m7.y & 1) << 1) | ((m7.z & 1) << 2) | ((m7.w & 1) << 3);
                int sh = lh * 4;
                wm = ((unsigned long long)n0 << sh) |
                     ((unsigned long long)n1 << (sh + 16)) |
                     ((unsigned long long)n2 << (sh + 32)) |
                     ((unsigned long long)n3 << (sh + 48));
                wm |= __shfl_xor(wm, 16);
                wm |= __shfl_xor(wm, 32);
            }

            // burst-load next group's mask (512B contiguous per row)
            if (g + 1 < NT / 2) {
                const char* mp = mwb + (size_t)(g + 1) * 512;
                m0 = *reinterpret_cast<const int4*>(mp);
                m1 = *reinterpret_cast<const int4*>(mp + 64);
                m2 = *reinterpret_cast<const int4*>(mp + 128);
                m3 = *reinterpret_cast<const int4*>(mp + 192);
                m4 = *reinterpret_cast<const int4*>(mp + 256);
                m5 = *reinterpret_cast<const int4*>(mp + 320);
                m6 = *reinterpret_cast<const int4*>(mp + 384);
                m7 = *reinterpret_cast<const int4*>(mp + 448);
            }
            __builtin_amdgcn_sched_barrier(0);

            // QK^T from Kt1
            f32x4v sc[4];
#pragma unroll
            for (int cb = 0; cb < 4; ++cb) {
                int kcol = cb * 16 + lr;
                bf16x8v bk0 = *reinterpret_cast<bf16x8v*>(
                    Kt1 + ((kcol * 128 + lh * 16) ^ ((kcol & 7) << 4)));
                bf16x8v bk1 = *reinterpret_cast<bf16x8v*>(
                    Kt1 + ((kcol * 128 + 64 + lh * 16) ^ ((kcol & 7) << 4)));
                f32x4v a = {0.f, 0.f, 0.f, 0.f};
                a = __builtin_amdgcn_mfma_f32_16x16x32_bf16(aq0, bk0, a, 0, 0, 0);
                a = __builtin_amdgcn_mfma_f32_16x16x32_bf16(aq1, bk1, a, 0, 0, 0);
                sc[cb] = a;
            }
#pragma unroll
            for (int r = 0; r < 4; ++r) {
                int q = 4 * lh + r;
                float rs = 0.f;
#pragma unroll
                for (int cb = 0; cb < 4; ++cb) {
                    float pv = __builtin_amdgcn_exp2f(sc[cb][r]);
                    rs += pv;
                    *reinterpret_cast<unsigned short*>(
                        PtB + ((q * 128 + (cb * 16 + lr) * 2) ^ ((q & 7) << 4))) = f2bf(pv);
                }
                psum[r] += rs;
            }
#pragma unroll
            for (int mh = 0; mh < 2; ++mh) {
                int k0 = mh * 32 + lh * 8;
                bf16x8v pa = *reinterpret_cast<bf16x8v*>(
                    PtB + ((lr * 128 + k0 * 2) ^ ((lr & 7) << 4)));
                unsigned mby = (unsigned)(wm >> ((mh * 4 + lh) * 8)) & 0xffu;
#pragma unroll
                for (int j = 0; j < 8; ++j)
                    pa[j] = (mby & (1u << j)) ? pa[j] : (short)0;
#pragma unroll
                for (int eb = 0; eb < 4; ++eb) {
                    int e = eb * 16 + lr;
                    bf16x8v vb = *reinterpret_cast<bf16x8v*>(
                        Vs1 + ((e * 128 + k0 * 2) ^ ((e & 7) << 4)));
                    Oa[eb] = __builtin_amdgcn_mfma_f32_16x16x32_bf16(pa, vb, Oa[eb], 0, 0, 0);
                }
            }
            // odd boundary: staging (4 oldest) landed; mask burst (8 newer)
            // stays in flight across the barrier.
            if (stg) {
                asm volatile("s_waitcnt vmcnt(8)" ::: "memory");
            } else {
                asm volatile("s_waitcnt vmcnt(0)" ::: "memory");
            }
            __builtin_amdgcn_s_barrier();
            __builtin_amdgcn_sched_barrier(0);
        }
    }

    // ---- epilogue: reduce denominators once; out = O * (1/0.9) / lsum
    constexpr float KEEP_INV = 1.0f / 0.9f;
    float* orow = out + ((size_t)bh * S_ + qbase) * E_;
#pragma unroll
    for (int r = 0; r < 4; ++r) {
        float s = psum[r];
#pragma unroll
        for (int off = 1; off < 16; off <<= 1)
            s += __shfl_xor(s, off);
        float inv = KEEP_INV / s;
        int q = 4 * lh + r;
#pragma unroll
        for (int eb = 0; eb < 4; ++eb)
            orow[(size_t)q * E_ + eb * 16 + lr] = Oa[eb][r] * inv;
    }
}

extern "C" void kernel_launch(void* const* d_in, const int* in_sizes, int n_in,
                              void* d_out, int out_size, void* d_ws, size_t ws_size,
                              hipStream_t stream) {
    (void)in_sizes; (void)n_in; (void)out_size; (void)ws_size;
    const float* query = (const float*)d_in[0];
    const float* key   = (const float*)d_in[1];
    const float* value = (const float*)d_in[2];
    const float* Wq    = (const float*)d_in[3];
    const float* bq    = (const float*)d_in[4];
    const float* Wk    = (const float*)d_in[5];
    const float* bk    = (const float*)d_in[6];
    const float* Wv    = (const float*)d_in[7];
    const float* bv    = (const float*)d_in[8];
    const int*   mask  = (const int*)d_in[9];
    float*       out   = (float*)d_out;

    const size_t per = (size_t)B_ * H_ * S_ * E_;
    __hip_bfloat16* qp  = (__hip_bfloat16*)d_ws;
    __hip_bfloat16* kp  = qp + per;
    __hip_bfloat16* vtp = kp + per;

    proj_kernel<<<B_ * (S_ / 16) * HSPLIT, 192, 0, stream>>>(query, key, value,
                                                             Wq, bq, Wk, bk, Wv, bv,
                                                             qp, kp, vtp);
    attn_kernel<<<B_ * H_ * (S_ / (QB * NW)), 256, 0, stream>>>(qp, kp, vtp, mask, out);
}

// Round 15
// 195.490 us; speedup vs baseline: 2.1174x; 2.1174x over previous
//
#include <hip/hip_runtime.h>
#include <hip/hip_bf16.h>

#define B_ 4
#define S_ 2048
#define H_ 8
#define E_ 64
#define NW 4      // waves per attention block
#define QB 16     // q rows per wave
#define KT 64     // k/v tile size
#define NT (S_ / KT)
#define HSPLIT 4  // proj: head-groups per s-tile (2 heads per block)

typedef __attribute__((ext_vector_type(8))) short bf16x8v;
typedef __attribute__((ext_vector_type(4))) float f32x4v;

static __device__ __forceinline__ unsigned short f2bf(float f) {
    __hip_bfloat16 h = __float2bfloat16(f);
    return *reinterpret_cast<unsigned short*>(&h);
}

// async global->LDS DMA, 16B/lane
static __device__ __forceinline__ void gl_lds16(const void* g, void* lds) {
    __builtin_amdgcn_global_load_lds(
        (const __attribute__((address_space(1))) unsigned int*)g,
        (__attribute__((address_space(3))) unsigned int*)lds, 16, 0, 0);
}

// ---------------------------------------------------------------------------
// Projection (R9, ~5us): q scaled into exp2 domain, K plain, V pre-transposed.
// grid = B * S/16 * HSPLIT, block = 192.
// ---------------------------------------------------------------------------
__global__ __launch_bounds__(192)
void proj_kernel(const float* __restrict__ query, const float* __restrict__ key,
                 const float* __restrict__ value,
                 const float* __restrict__ Wq, const float* __restrict__ bq,
                 const float* __restrict__ Wk, const float* __restrict__ bk,
                 const float* __restrict__ Wv, const float* __restrict__ bv,
                 __hip_bfloat16* __restrict__ qp, __hip_bfloat16* __restrict__ kp,
                 __hip_bfloat16* __restrict__ vtp)
{
    const int tid  = threadIdx.x;
    const int wave = tid >> 6;
    const int lane = tid & 63;
    const int lr   = lane & 15;
    const int lh   = lane >> 4;
    const int ntile = S_ / 16;
    const int hb    = blockIdx.x % HSPLIT;
    const int sbase = ((blockIdx.x / HSPLIT) % ntile) * 16;
    const int b     = blockIdx.x / (ntile * HSPLIT);

    const float* x    = (wave == 0) ? query : (wave == 1) ? key : value;
    const float* W    = (wave == 0) ? Wq    : (wave == 1) ? Wk  : Wv;
    const float* bias = (wave == 0) ? bq    : (wave == 1) ? bk  : bv;

    bf16x8v wf[4][2];
#pragma unroll
    for (int cb = 0; cb < 4; ++cb)
#pragma unroll
        for (int hf = 0; hf < 2; ++hf)
#pragma unroll
            for (int j = 0; j < 8; ++j) {
                int e = lh * 8 + j + 32 * hf;
                wf[cb][hf][j] = (short)f2bf(W[e * E_ + cb * 16 + lr]);
            }

    float4 bias4[4];
    float  bvals[4];
#pragma unroll
    for (int cb = 0; cb < 4; ++cb) {
        bias4[cb] = *reinterpret_cast<const float4*>(bias + cb * 16 + 4 * lh);
        bvals[cb] = bias[cb * 16 + lr];
    }

    const float QSCALE = 0.18033688011112042f;   // log2e / 8

#pragma unroll
    for (int hi = 0; hi < H_ / HSPLIT; ++hi) {
        const int h = hb * (H_ / HSPLIT) + hi;
        const float* xrow = x + (((size_t)b * S_ + sbase + lr) * H_ + h) * E_;
        const float4* xr = reinterpret_cast<const float4*>(xrow);
        float4 a0 = xr[lh * 2], a1 = xr[lh * 2 + 1];
        float4 a2 = xr[8 + lh * 2], a3 = xr[8 + lh * 2 + 1];
        bf16x8v af[2];
        af[0][0] = (short)f2bf(a0.x); af[0][1] = (short)f2bf(a0.y);
        af[0][2] = (short)f2bf(a0.z); af[0][3] = (short)f2bf(a0.w);
        af[0][4] = (short)f2bf(a1.x); af[0][5] = (short)f2bf(a1.y);
        af[0][6] = (short)f2bf(a1.z); af[0][7] = (short)f2bf(a1.w);
        af[1][0] = (short)f2bf(a2.x); af[1][1] = (short)f2bf(a2.y);
        af[1][2] = (short)f2bf(a2.z); af[1][3] = (short)f2bf(a2.w);
        af[1][4] = (short)f2bf(a3.x); af[1][5] = (short)f2bf(a3.y);
        af[1][6] = (short)f2bf(a3.z); af[1][7] = (short)f2bf(a3.w);

        if (wave < 2) {
            __hip_bfloat16* dst = (wave == 0) ? qp : kp;
            const float scl = (wave == 0) ? QSCALE : 1.0f;
#pragma unroll
            for (int cb = 0; cb < 4; ++cb) {
                f32x4v acc = {0.f, 0.f, 0.f, 0.f};
                acc = __builtin_amdgcn_mfma_f32_16x16x32_bf16(wf[cb][0], af[0], acc, 0, 0, 0);
                acc = __builtin_amdgcn_mfma_f32_16x16x32_bf16(wf[cb][1], af[1], acc, 0, 0, 0);
                ushort4 o;
                o.x = f2bf((acc[0] + bias4[cb].x) * scl);
                o.y = f2bf((acc[1] + bias4[cb].y) * scl);
                o.z = f2bf((acc[2] + bias4[cb].z) * scl);
                o.w = f2bf((acc[3] + bias4[cb].w) * scl);
                *reinterpret_cast<ushort4*>(
                    (unsigned short*)dst +
                    (((size_t)b * H_ + h) * S_ + sbase + lr) * E_ + cb * 16 + 4 * lh) = o;
            }
        } else {
#pragma unroll
            for (int cb = 0; cb < 4; ++cb) {
                f32x4v acc = {0.f, 0.f, 0.f, 0.f};
                acc = __builtin_amdgcn_mfma_f32_16x16x32_bf16(af[0], wf[cb][0], acc, 0, 0, 0);
                acc = __builtin_amdgcn_mfma_f32_16x16x32_bf16(af[1], wf[cb][1], acc, 0, 0, 0);
                float bv4 = bvals[cb];
                ushort4 o;
                o.x = f2bf(acc[0] + bv4);
                o.y = f2bf(acc[1] + bv4);
                o.z = f2bf(acc[2] + bv4);
                o.w = f2bf(acc[3] + bv4);
                *reinterpret_cast<ushort4*>(
                    (unsigned short*)vtp +
                    (((size_t)b * H_ + h) * E_ + cb * 16 + lr) * S_ + sbase + 4 * lh) = o;
            }
        }
    }
}

// ---------------------------------------------------------------------------
// Flash attention = R14 (2-tile 512B mask bursts, counted boundaries) with
// the VGPR cap lifted: __launch_bounds__(256, 2) so the 8 live int4 mask
// regs stay in registers (R14 spilled at the compiler's 64-VGPR target ->
// +0.5GB scratch traffic). Occupancy remains LDS-capped at 4 blocks/CU.
// grid = B*H * S/(QB*NW) = 1024, block = 256
// ---------------------------------------------------------------------------
__global__ __launch_bounds__(256, 2)
void attn_kernel(const __hip_bfloat16* __restrict__ qp,
                 const __hip_bfloat16* __restrict__ kp,
                 const __hip_bfloat16* __restrict__ vtp,
                 const int* __restrict__ mask,
                 float* __restrict__ out)
{
    __shared__ unsigned short Kt[2][KT * E_];    // swizzled [k][e], dbuf
    __shared__ unsigned short Vs[2][KT * E_];    // swizzled [e][k], dbuf
    __shared__ unsigned short Pt[NW][16 * KT];   // swizzled [q][k], per wave

    const int tid  = threadIdx.x;
    const int wave = tid >> 6;
    const int lane = tid & 63;
    const int lr   = lane & 15;
    const int lh   = lane >> 4;
    const int nqt  = S_ / (QB * NW);
    const int bh   = blockIdx.x / nqt;
    const int qt   = blockIdx.x % nqt;
    const int qbase = qt * (QB * NW) + wave * QB;

    const __hip_bfloat16* qrow = qp + ((size_t)bh * S_ + qbase + lr) * E_;
    bf16x8v aq0 = *reinterpret_cast<const bf16x8v*>(qrow + lh * 8);
    bf16x8v aq1 = *reinterpret_cast<const bf16x8v*>(qrow + lh * 8 + 32);

    float psum[4];
    f32x4v Oa[4];
#pragma unroll
    for (int r = 0; r < 4; ++r) psum[r] = 0.f;
#pragma unroll
    for (int eb = 0; eb < 4; ++eb) Oa[eb] = {0.f, 0.f, 0.f, 0.f};

    const char* kgb = (const char*)(kp  + (size_t)bh * S_ * E_);
    const char* vgb = (const char*)(vtp + (size_t)bh * E_ * S_);
    // mask base: lane covers row lr, 16B chunk lh; group g = bytes
    // [g*512, g*512+512) of the row (2 tiles x 256B)
    const char* mwb = (const char*)mask +
        (((size_t)bh * S_ + qbase + lr) * S_) * 4 + lh * 16;

    const int rowA = wave * 16 + (lane >> 3);
    const int rowB = rowA + 8;
    const int e2   = (((lane & 7) ^ (lane >> 3)) << 4);
    const size_t koffA = (size_t)rowA * 128 + e2;
    const size_t koffB = (size_t)rowB * 128 + e2;
    const size_t voffA = (size_t)rowA * (S_ * 2) + e2;
    const size_t voffB = (size_t)rowB * (S_ * 2) + e2;

    char* Kt0 = (char*)(Kt[0]); char* Kt1 = (char*)(Kt[1]);
    char* Vs0 = (char*)(Vs[0]); char* Vs1 = (char*)(Vs[1]);
    char* PtB = (char*)(Pt[wave]);

    // mask regs: one 2-tile group (512B/row). m0..m3 = even tile, m4..m7 = odd
    int4 m0, m1, m2, m3, m4, m5, m6, m7;

    // ---- prologue: stage tile 0 (oldest 4 vmem); group-0 mask burst (8)
    gl_lds16(kgb + koffA, Kt0 + wave * 2048);
    gl_lds16(kgb + koffB, Kt0 + wave * 2048 + 1024);
    gl_lds16(vgb + voffA, Vs0 + wave * 2048);
    gl_lds16(vgb + voffB, Vs0 + wave * 2048 + 1024);
    __builtin_amdgcn_sched_barrier(0);
    m0 = *reinterpret_cast<const int4*>(mwb);
    m1 = *reinterpret_cast<const int4*>(mwb + 64);
    m2 = *reinterpret_cast<const int4*>(mwb + 128);
    m3 = *reinterpret_cast<const int4*>(mwb + 192);
    m4 = *reinterpret_cast<const int4*>(mwb + 256);
    m5 = *reinterpret_cast<const int4*>(mwb + 320);
    m6 = *reinterpret_cast<const int4*>(mwb + 384);
    m7 = *reinterpret_cast<const int4*>(mwb + 448);
    __builtin_amdgcn_sched_barrier(0);
    asm volatile("s_waitcnt vmcnt(8)" ::: "memory");
    __builtin_amdgcn_s_barrier();
    __builtin_amdgcn_sched_barrier(0);

    for (int g = 0; g < NT / 2; ++g) {
        // ================= EVEN tile: kt = 2g (uses buf0, stages buf1) =====
        {
            const int kt = 2 * g;
            const int kb = kt * KT;
            {
                const size_t kadd = (size_t)(kb + KT) * 128;
                const size_t vadd = (size_t)(kb + KT) * 2;
                gl_lds16(kgb + kadd + koffA, Kt1 + wave * 2048);
                gl_lds16(kgb + kadd + koffB, Kt1 + wave * 2048 + 1024);
                gl_lds16(vgb + vadd + voffA, Vs1 + wave * 2048);
                gl_lds16(vgb + vadd + voffB, Vs1 + wave * 2048 + 1024);
            }
            __builtin_amdgcn_sched_barrier(0);

            // pack even-tile mask from m0..m3
            unsigned long long wm;
            {
                unsigned n0 = (m0.x & 1) | ((m0.y & 1) << 1) | ((m0.z & 1) << 2) | ((m0.w & 1) << 3);
                unsigned n1 = (m1.x & 1) | ((m1.y & 1) << 1) | ((m1.z & 1) << 2) | ((m1.w & 1) << 3);
                unsigned n2 = (m2.x & 1) | ((m2.y & 1) << 1) | ((m2.z & 1) << 2) | ((m2.w & 1) << 3);
                unsigned n3 = (m3.x & 1) | ((m3.y & 1) << 1) | ((m3.z & 1) << 2) | ((m3.w & 1) << 3);
                int sh = lh * 4;
                wm = ((unsigned long long)n0 << sh) |
                     ((unsigned long long)n1 << (sh + 16)) |
                     ((unsigned long long)n2 << (sh + 32)) |
                     ((unsigned long long)n3 << (sh + 48));
                wm |= __shfl_xor(wm, 16);
                wm |= __shfl_xor(wm, 32);
            }

            // QK^T from Kt0
            f32x4v sc[4];
#pragma unroll
            for (int cb = 0; cb < 4; ++cb) {
                int kcol = cb * 16 + lr;
                bf16x8v bk0 = *reinterpret_cast<bf16x8v*>(
                    Kt0 + ((kcol * 128 + lh * 16) ^ ((kcol & 7) << 4)));
                bf16x8v bk1 = *reinterpret_cast<bf16x8v*>(
                    Kt0 + ((kcol * 128 + 64 + lh * 16) ^ ((kcol & 7) << 4)));
                f32x4v a = {0.f, 0.f, 0.f, 0.f};
                a = __builtin_amdgcn_mfma_f32_16x16x32_bf16(aq0, bk0, a, 0, 0, 0);
                a = __builtin_amdgcn_mfma_f32_16x16x32_bf16(aq1, bk1, a, 0, 0, 0);
                sc[cb] = a;
            }
#pragma unroll
            for (int r = 0; r < 4; ++r) {
                int q = 4 * lh + r;
                float rs = 0.f;
#pragma unroll
                for (int cb = 0; cb < 4; ++cb) {
                    float pv = __builtin_amdgcn_exp2f(sc[cb][r]);
                    rs += pv;
                    *reinterpret_cast<unsigned short*>(
                        PtB + ((q * 128 + (cb * 16 + lr) * 2) ^ ((q & 7) << 4))) = f2bf(pv);
                }
                psum[r] += rs;
            }
#pragma unroll
            for (int mh = 0; mh < 2; ++mh) {
                int k0 = mh * 32 + lh * 8;
                bf16x8v pa = *reinterpret_cast<bf16x8v*>(
                    PtB + ((lr * 128 + k0 * 2) ^ ((lr & 7) << 4)));
                unsigned mby = (unsigned)(wm >> ((mh * 4 + lh) * 8)) & 0xffu;
#pragma unroll
                for (int j = 0; j < 8; ++j)
                    pa[j] = (mby & (1u << j)) ? pa[j] : (short)0;
#pragma unroll
                for (int eb = 0; eb < 4; ++eb) {
                    int e = eb * 16 + lr;
                    bf16x8v vb = *reinterpret_cast<bf16x8v*>(
                        Vs0 + ((e * 128 + k0 * 2) ^ ((e & 7) << 4)));
                    Oa[eb] = __builtin_amdgcn_mfma_f32_16x16x32_bf16(pa, vb, Oa[eb], 0, 0, 0);
                }
            }
            // even boundary: full drain (mask loads are ~1 tile old, landed)
            asm volatile("s_waitcnt vmcnt(0)" ::: "memory");
            __builtin_amdgcn_s_barrier();
            __builtin_amdgcn_sched_barrier(0);
        }

        // ================= ODD tile: kt = 2g+1 (uses buf1, stages buf0) ====
        {
            const int kt = 2 * g + 1;
            const int kb = kt * KT;
            const bool stg = (kt + 1 < NT);
            if (stg) {
                const size_t kadd = (size_t)(kb + KT) * 128;
                const size_t vadd = (size_t)(kb + KT) * 2;
                gl_lds16(kgb + kadd + koffA, Kt0 + wave * 2048);
                gl_lds16(kgb + kadd + koffB, Kt0 + wave * 2048 + 1024);
                gl_lds16(vgb + vadd + voffA, Vs0 + wave * 2048);
                gl_lds16(vgb + vadd + voffB, Vs0 + wave * 2048 + 1024);
            }
            __builtin_amdgcn_sched_barrier(0);

            // pack odd-tile mask from m4..m7 (consumed BEFORE the reload)
            unsigned long long wm;
            {
                unsigned n0 = (m4.x & 1) | ((m4.y & 1) << 1) | ((m4.z & 1) << 2) | ((m4.w & 1) << 3);
                unsigned n1 = (m5.x & 1) | ((m5.y & 1) << 1) | ((m5.z & 1) << 2) | ((m5.w & 1) << 3);
                unsigned n2 = (m6.x & 1) | ((m6.y & 1) << 1) | ((m6.z & 1) << 2) | ((m6.w & 1) << 3);
                unsigned n3 = (m7.x & 1) | ((m7.y & 1) << 1) | ((m7.z & 1) << 2) | ((m7.w & 1) << 3);
                int sh = lh * 4;
                wm = ((unsigned long long)n0 << sh) |
                     ((unsigned long long)n1 << (sh + 16)) |
                     ((unsigned long long)n2 << (sh + 32)) |
                     ((unsigned long long)n3 << (sh + 48));
                wm |= __shfl_xor(wm, 16);
                wm |= __shfl_xor(wm, 32);
            }

            // burst-load next group's mask (512B contiguous per row)
            if (g + 1 < NT / 2) {
                const char* mp = mwb + (size_t)(g + 1) * 512;
                m0 = *reinterpret_cast<const int4*>(mp);
                m1 = *reinterpret_cast<const int4*>(mp + 64);
                m2 = *reinterpret_cast<const int4*>(mp + 128);
                m3 = *reinterpret_cast<const int4*>(mp + 192);
                m4 = *reinterpret_cast<const int4*>(mp + 256);
                m5 = *reinterpret_cast<const int4*>(mp + 320);
                m6 = *reinterpret_cast<const int4*>(mp + 384);
                m7 = *reinterpret_cast<const int4*>(mp + 448);
            }
            __builtin_amdgcn_sched_barrier(0);

            // QK^T from Kt1
            f32x4v sc[4];
#pragma unroll
            for (int cb = 0; cb < 4; ++cb) {
                int kcol = cb * 16 + lr;
                bf16x8v bk0 = *reinterpret_cast<bf16x8v*>(
                    Kt1 + ((kcol * 128 + lh * 16) ^ ((kcol & 7) << 4)));
                bf16x8v bk1 = *reinterpret_cast<bf16x8v*>(
                    Kt1 + ((kcol * 128 + 64 + lh * 16) ^ ((kcol & 7) << 4)));
                f32x4v a = {0.f, 0.f, 0.f, 0.f};
                a = __builtin_amdgcn_mfma_f32_16x16x32_bf16(aq0, bk0, a, 0, 0, 0);
                a = __builtin_amdgcn_mfma_f32_16x16x32_bf16(aq1, bk1, a, 0, 0, 0);
                sc[cb] = a;
            }
#pragma unroll
            for (int r = 0; r < 4; ++r) {
                int q = 4 * lh + r;
                float rs = 0.f;
#pragma unroll
                for (int cb = 0; cb < 4; ++cb) {
                    float pv = __builtin_amdgcn_exp2f(sc[cb][r]);
                    rs += pv;
                    *reinterpret_cast<unsigned short*>(
                        PtB + ((q * 128 + (cb * 16 + lr) * 2) ^ ((q & 7) << 4))) = f2bf(pv);
                }
                psum[r] += rs;
            }
#pragma unroll
            for (int mh = 0; mh < 2; ++mh) {
                int k0 = mh * 32 + lh * 8;
                bf16x8v pa = *reinterpret_cast<bf16x8v*>(
                    PtB + ((lr * 128 + k0 * 2) ^ ((lr & 7) << 4)));
                unsigned mby = (unsigned)(wm >> ((mh * 4 + lh) * 8)) & 0xffu;
#pragma unroll
                for (int j = 0; j < 8; ++j)
                    pa[j] = (mby & (1u << j)) ? pa[j] : (short)0;
#pragma unroll
                for (int eb = 0; eb < 4; ++eb) {
                    int e = eb * 16 + lr;
                    bf16x8v vb = *reinterpret_cast<bf16x8v*>(
                        Vs1 + ((e * 128 + k0 * 2) ^ ((e & 7) << 4)));
                    Oa[eb] = __builtin_amdgcn_mfma_f32_16x16x32_bf16(pa, vb, Oa[eb], 0, 0, 0);
                }
            }
            // odd boundary: staging (4 oldest) landed; mask burst (8 newer)
            // stays in flight across the barrier.
            if (stg) {
                asm volatile("s_waitcnt vmcnt(8)" ::: "memory");
            } else {
                asm volatile("s_waitcnt vmcnt(0)" ::: "memory");
            }
            __builtin_amdgcn_s_barrier();
            __builtin_amdgcn_sched_barrier(0);
        }
    }

    // ---- epilogue: reduce denominators once; out = O * (1/0.9) / lsum
    constexpr float KEEP_INV = 1.0f / 0.9f;
    float* orow = out + ((size_t)bh * S_ + qbase) * E_;
#pragma unroll
    for (int r = 0; r < 4; ++r) {
        float s = psum[r];
#pragma unroll
        for (int off = 1; off < 16; off <<= 1)
            s += __shfl_xor(s, off);
        float inv = KEEP_INV / s;
        int q = 4 * lh + r;
#pragma unroll
        for (int eb = 0; eb < 4; ++eb)
            orow[(size_t)q * E_ + eb * 16 + lr] = Oa[eb][r] * inv;
    }
}

extern "C" void kernel_launch(void* const* d_in, const int* in_sizes, int n_in,
                              void* d_out, int out_size, void* d_ws, size_t ws_size,
                              hipStream_t stream) {
    (void)in_sizes; (void)n_in; (void)out_size; (void)ws_size;
    const float* query = (const float*)d_in[0];
    const float* key   = (const float*)d_in[1];
    const float* value = (const float*)d_in[2];
    const float* Wq    = (const float*)d_in[3];
    const float* bq    = (const float*)d_in[4];
    const float* Wk    = (const float*)d_in[5];
    const float* bk    = (const float*)d_in[6];
    const float* Wv    = (const float*)d_in[7];
    const float* bv    = (const float*)d_in[8];
    const int*   mask  = (const int*)d_in[9];
    float*       out   = (float*)d_out;

    const size_t per = (size_t)B_ * H_ * S_ * E_;
    __hip_bfloat16* qp  = (__hip_bfloat16*)d_ws;
    __hip_bfloat16* kp  = qp + per;
    __hip_bfloat16* vtp = kp + per;

    proj_kernel<<<B_ * (S_ / 16) * HSPLIT, 192, 0, stream>>>(query, key, value,
                                                             Wq, bq, Wk, bk, Wv, bv,
                                                             qp, kp, vtp);
    attn_kernel<<<B_ * H_ * (S_ / (QB * NW)), 256, 0, stream>>>(qp, kp, vtp, mask, out);
}